// Round 13
// baseline (106.722 us; speedup 1.0000x reference)
//
#include <hip/hip_runtime.h>
#include <hip/hip_fp8.h>

typedef int v8i __attribute__((ext_vector_type(8)));
typedef float f32x4 __attribute__((ext_vector_type(4)));

#define N_TOTAL 262144
#define D 128
#define K_TOTAL 1024
#define BN 128
#define NBLK (N_TOTAL / BN)  // 2048
#define BIGF 256.0f
#define TILEB 8192  // 64 centroids x 128 dims x 1 B fp8, 16x16x128-operand order
#define NT 16

__device__ __forceinline__ unsigned f2fp8(float x) {
  return (unsigned)__hip_fp8_e4m3(x).__x;
}
__device__ __forceinline__ unsigned umx(unsigned a, unsigned b) {
  return a > b ? a : b;
}

// Kernel 1: codebook fp32 -> fp8 e4m3 packed in EXACT 16x16x128 B-operand
// order: tile ts (64 centroids) / col-group cgc (16 centroids): lane
// l = kq*16 + c reads its 32 contiguous bytes (dims kq*32..+31 of centroid c)
// at ts*8192 + cgc*2048 + l*32. Also emits bigm2 = BIG - 0.5||m||^2.
__global__ void prep_means(const float* __restrict__ means,
                           unsigned char* __restrict__ mbf8,
                           float* __restrict__ bigm2) {
  int k = blockIdx.x, t = threadIdx.x;  // 1024 blocks x 64 threads
  int ts = k >> 6, c64 = k & 63;
  int cgc = c64 >> 4, c = c64 & 15;
  unsigned char* tb = mbf8 + ts * TILEB + cgc * 2048;
  float v0 = means[k * D + 2 * t];
  float v1 = means[k * D + 2 * t + 1];
#pragma unroll
  for (int i = 0; i < 2; ++i) {
    int d = 2 * t + i;
    int kq = d >> 5, rem = d & 31;
    tb[(kq * 16 + c) * 32 + rem] = (unsigned char)f2fp8(i ? v1 : v0);
  }
  float s = v0 * v0 + v1 * v1;
#pragma unroll
  for (int m = 32; m; m >>= 1) s += __shfl_down(s, m, 64);
  if (t == 0) bigm2[k] = BIGF - 0.5f * s;
}

union BOp {
  uint4 q[2];
  v8i v;
};

// Kernel 2: 128 rows/block, 4 waves x 32 rows (2 row-groups of 16).
// mfma_scale_f32_16x16x128_f8f6f4: full-D dot per MFMA, 4-reg acc, no
// chains -> live set ~60 VGPR, (256,8) reachable -> 8-waves/SIMD band.
// T14 reg-staging, mid-tile ds_write, linear operand-order LDS (0 conflicts).
__global__ __launch_bounds__(256, 8) void kmeans_main(
    const float* __restrict__ X, const unsigned char* __restrict__ mbf8,
    const float* __restrict__ bigm2, const float* __restrict__ means,
    float* __restrict__ partials) {
  __shared__ __attribute__((aligned(16))) char Bs[2][TILEB];  // 16 KB dbuf
  __shared__ float m2s[K_TOTAL];                              // 4 KB
  __shared__ int idxs[BN];
  __shared__ float wsum[4];

  const int t = threadIdx.x;
  const int l = t & 63;
  const int w = t >> 6;
  const int lr = l & 15;   // row-in-group for A; centroid-in-group for B
  const int kq = l >> 4;   // k-quarter (32-byte slice of D=128)
  const int rot = blockIdx.x & 15;
  const long nbase = (long)blockIdx.x * BN;

  // ---- A fragments: row-group g: row nbase+w*32+g*16+lr, dims kq*32..+31 ----
  v8i af[2];
#pragma unroll
  for (int g = 0; g < 2; ++g) {
    const float* xr = X + (nbase + w * 32 + g * 16 + lr) * D + kq * 32;
    v8i av;
#pragma unroll
    for (int j = 0; j < 8; ++j) {
      float4 v = *(const float4*)(xr + j * 4);
      av[j] = (int)(f2fp8(v.x) | (f2fp8(v.y) << 8) | (f2fp8(v.z) << 16) |
                    (f2fp8(v.w) << 24));
    }
    af[g] = av;
  }

  // ---- stage bigm2 into LDS (once, all 16 tiles) ----
  {
    float4 v = ((const float4*)bigm2)[t];  // 256*4 = 1024
    *(float4*)(m2s + t * 4) = v;
  }

  unsigned bk[8];  // running packed keys: [g*4 + reg]
#pragma unroll
  for (int e = 0; e < 8; ++e) bk[e] = 0u;

  // ---- prologue: stage tile `rot` (pure linear copy, conflict-free) ----
  {
    const char* src = (const char*)mbf8 + rot * TILEB;
    uint4 s0 = *(const uint4*)(src + t * 16);
    uint4 s1 = *(const uint4*)(src + 4096 + t * 16);
    *(uint4*)(Bs[0] + t * 16) = s0;
    *(uint4*)(Bs[0] + 4096 + t * 16) = s1;
  }
  __syncthreads();

#define COMPUTE_CGC(TID, BP, CGC)                                              \
  {                                                                            \
    float m2v_ = m2s[(TID) * 64 + (CGC) * 16 + lr];                            \
    f32x4 ci_ = {m2v_, m2v_, m2v_, m2v_};                                      \
    BOp bu_;                                                                   \
    bu_.q[0] = *(const uint4*)((BP) + (CGC) * 2048 + l * 32);                  \
    bu_.q[1] = *(const uint4*)((BP) + (CGC) * 2048 + l * 32 + 16);             \
    unsigned kk_ = (unsigned)((TID) * 64 + (CGC) * 16) | (unsigned)lr;         \
    _Pragma("unroll") for (int g_ = 0; g_ < 2; ++g_) {                         \
      f32x4 acc_ = __builtin_amdgcn_mfma_scale_f32_16x16x128_f8f6f4(           \
          af[g_], bu_.v, ci_, 0, 0, 0, 127, 0, 127);                           \
      _Pragma("unroll") for (int e_ = 0; e_ < 4; ++e_) {                       \
        unsigned key_ = (__float_as_uint(acc_[e_]) & 0xFFFFFC00u) | kk_;       \
        bk[g_ * 4 + e_] = umx(bk[g_ * 4 + e_], key_);                          \
      }                                                                        \
    }                                                                          \
  }

  int cur = 0;
  for (int ks = 0; ks < NT; ++ks) {
    const int tid = (rot + ks) & 15;
    uint4 s0, s1;
    if (ks < NT - 1) {
      // issue next tile's global loads EARLY (latency hides under compute)
      const char* src = (const char*)mbf8 + (((rot + ks + 1) & 15) * TILEB);
      s0 = *(const uint4*)(src + t * 16);
      s1 = *(const uint4*)(src + 4096 + t * 16);
    }
    const char* bp = Bs[cur];
    COMPUTE_CGC(tid, bp, 0);
    COMPUTE_CGC(tid, bp, 1);
    if (ks < NT - 1) {
      // mid-tile write: staging regs die here; Bs[cur^1] not being read
      char* dst = Bs[cur ^ 1];
      *(uint4*)(dst + t * 16) = s0;
      *(uint4*)(dst + 4096 + t * 16) = s1;
    }
    COMPUTE_CGC(tid, bp, 2);
    COMPUTE_CGC(tid, bp, 3);
    __syncthreads();
    cur ^= 1;
  }
#undef COMPUTE_CGC

  // ---- reduce keys across the 16 centroid-lanes of each kq-group ----
  // key slot (g, reg) holds row g*16 + kq*4 + reg; lanes lr=0..15 share it.
#pragma unroll
  for (int e = 0; e < 8; ++e) {
    unsigned k = bk[e];
#pragma unroll
    for (int m = 1; m < 16; m <<= 1) {
      unsigned o = (unsigned)__shfl_xor((int)k, m, 64);
      k = umx(k, o);
    }
    if (lr == 0) {
      int rowc = (e >> 2) * 16 + kq * 4 + (e & 3);
      idxs[w * 32 + rowc] = (int)(k & 1023u);
    }
  }
  __syncthreads();

  // ---- exact fp32 loss for assigned centroids (2 threads per row) ----
  {
    int r2 = t >> 1, h = t & 1;
    long n = nbase + r2;
    int ai = idxs[r2];
    const float4* xr = (const float4*)(X + n * D + h * 64);
    const float4* mr = (const float4*)(means + (long)ai * D + h * 64);
    float s = 0.f;
#pragma unroll
    for (int i = 0; i < 16; ++i) {
      float4 xv = xr[i];
      float4 mv = mr[i];
      float d0 = xv.x - mv.x, d1 = xv.y - mv.y;
      float d2 = xv.z - mv.z, d3 = xv.w - mv.w;
      s = fmaf(d0, d0, s);
      s = fmaf(d1, d1, s);
      s = fmaf(d2, d2, s);
      s = fmaf(d3, d3, s);
    }
#pragma unroll
    for (int m = 32; m; m >>= 1) s += __shfl_down(s, m, 64);
    if (l == 0) wsum[w] = s;
  }
  __syncthreads();
  if (t == 0) partials[blockIdx.x] = wsum[0] + wsum[1] + wsum[2] + wsum[3];
}

// Kernel 3: deterministic fixed-order final reduction (double accum).
__global__ void reduce_loss(const float* __restrict__ partials,
                            float* __restrict__ out) {
  __shared__ double ws[4];
  int t = threadIdx.x;
  double s = 0.0;
  for (int i = t; i < NBLK; i += 256) s += (double)partials[i];
#pragma unroll
  for (int m = 32; m; m >>= 1) s += __shfl_down(s, m, 64);
  if ((t & 63) == 0) ws[t >> 6] = s;
  __syncthreads();
  if (t == 0) out[0] = (float)(ws[0] + ws[1] + ws[2] + ws[3]);
}

extern "C" void kernel_launch(void* const* d_in, const int* in_sizes, int n_in,
                              void* d_out, int out_size, void* d_ws,
                              size_t ws_size, hipStream_t stream) {
  const float* X = (const float*)d_in[0];
  const float* means = (const float*)d_in[1];
  float* out = (float*)d_out;
  char* ws = (char*)d_ws;
  unsigned char* mbf8 = (unsigned char*)ws;         // 131072 B
  float* bigm2 = (float*)(ws + 131072);             // 4096 B
  float* partials = (float*)(ws + 131072 + 4096);   // 8192 B

  prep_means<<<K_TOTAL, 64, 0, stream>>>(means, mbf8, bigm2);
  kmeans_main<<<NBLK, 256, 0, stream>>>(X, mbf8, bigm2, means, partials);
  reduce_loss<<<1, 256, 0, stream>>>(partials, out);
}

// Round 14
// 60.400 us; speedup vs baseline: 1.7669x; 1.7669x over previous
//
#include <hip/hip_runtime.h>
#include <hip/hip_fp8.h>

typedef int v8i __attribute__((ext_vector_type(8)));
typedef float f32x4 __attribute__((ext_vector_type(4)));

#define N_TOTAL 262144
#define D 128
#define K_TOTAL 1024
#define BN 128
#define NBLK (N_TOTAL / BN)  // 2048
#define TILEB 8192  // 64 centroids x 128 dims x 1 B fp8, 16x16x128-operand order
#define NT 16

__device__ __forceinline__ unsigned f2fp8(float x) {
  return (unsigned)__hip_fp8_e4m3(x).__x;
}

// Kernel 1: codebook fp32 -> fp8 e4m3 packed in EXACT 16x16x128 B-operand
// order (lane l = kq*16 + c reads its 32 contiguous bytes at cgc*2048 + l*32).
// Also emits nm2[k] = -0.5*||m||^2 (exact fp32).
__global__ void prep_means(const float* __restrict__ means,
                           unsigned char* __restrict__ mbf8,
                           float* __restrict__ nm2) {
  int k = blockIdx.x, t = threadIdx.x;  // 1024 blocks x 64 threads
  int ts = k >> 6, c64 = k & 63;
  int cgc = c64 >> 4, c = c64 & 15;
  unsigned char* tb = mbf8 + ts * TILEB + cgc * 2048;
  float v0 = means[k * D + 2 * t];
  float v1 = means[k * D + 2 * t + 1];
#pragma unroll
  for (int i = 0; i < 2; ++i) {
    int d = 2 * t + i;
    int kq = d >> 5, rem = d & 31;
    tb[(kq * 16 + c) * 32 + rem] = (unsigned char)f2fp8(i ? v1 : v0);
  }
  float s = v0 * v0 + v1 * v1;
#pragma unroll
  for (int m = 32; m; m >>= 1) s += __shfl_down(s, m, 64);
  if (t == 0) nm2[k] = -0.5f * s;
}

union BOp {
  uint4 q[2];
  v8i v;
};

// Kernel 2: NO index/gather path. loss = sum(x2) - 2*sum_rows max_k(score).
// Per row: running float max of (x.m - 0.5||m||^2) via MFMA C-init; x2 exact
// fp32 from the A-load pass. 128 rows/block, 4 waves x 32 rows,
// mfma_scale_f32_16x16x128_f8f6f4, T14 reg-staging, linear operand-order LDS.
__global__ __launch_bounds__(256) void kmeans_main(
    const float* __restrict__ X, const unsigned char* __restrict__ mbf8,
    const float* __restrict__ nm2, float* __restrict__ partials) {
  __shared__ __attribute__((aligned(16))) char Bs[2][TILEB];  // 16 KB dbuf
  __shared__ float m2s[K_TOTAL];                              // 4 KB
  __shared__ float x2s[BN];                                   // 512 B
  __shared__ float wsum[4];

  const int t = threadIdx.x;
  const int l = t & 63;
  const int w = t >> 6;
  const int lr = l & 15;  // row-in-group for A; centroid-in-group for B
  const int kq = l >> 4;  // k-quarter (32-float slice of D=128)
  const int rot = blockIdx.x & 15;
  const long nbase = (long)blockIdx.x * BN;

  // ---- A fragments + exact fp32 ||x||^2 partials ----
  v8i af[2];
  float psq[2];
#pragma unroll
  for (int g = 0; g < 2; ++g) {
    const float* xr = X + (nbase + w * 32 + g * 16 + lr) * D + kq * 32;
    v8i av;
    float sq = 0.f;
#pragma unroll
    for (int j = 0; j < 8; ++j) {
      float4 v = *(const float4*)(xr + j * 4);
      sq = fmaf(v.x, v.x, sq);
      sq = fmaf(v.y, v.y, sq);
      sq = fmaf(v.z, v.z, sq);
      sq = fmaf(v.w, v.w, sq);
      av[j] = (int)(f2fp8(v.x) | (f2fp8(v.y) << 8) | (f2fp8(v.z) << 16) |
                    (f2fp8(v.w) << 24));
    }
    af[g] = av;
    psq[g] = sq;
  }
  // reduce x2 over the 4 kq-lanes of each row; kq==0 lane stores to LDS
#pragma unroll
  for (int g = 0; g < 2; ++g) {
    float s2 = psq[g];
    s2 += __shfl_xor(s2, 16, 64);
    s2 += __shfl_xor(s2, 32, 64);
    if (kq == 0) x2s[w * 32 + g * 16 + lr] = s2;
  }

  // ---- stage nm2 into LDS (once, all 16 tiles) ----
  {
    float4 v = ((const float4*)nm2)[t];  // 256*4 = 1024
    *(float4*)(m2s + t * 4) = v;
  }

  float bs[8];  // running row maxes: [g*4 + reg]
#pragma unroll
  for (int e = 0; e < 8; ++e) bs[e] = -3.402823466e38f;

  // ---- prologue: stage tile `rot` (pure linear copy, conflict-free) ----
  {
    const char* src = (const char*)mbf8 + rot * TILEB;
    uint4 s0 = *(const uint4*)(src + t * 16);
    uint4 s1 = *(const uint4*)(src + 4096 + t * 16);
    *(uint4*)(Bs[0] + t * 16) = s0;
    *(uint4*)(Bs[0] + 4096 + t * 16) = s1;
  }
  __syncthreads();

#define COMPUTE_CGC(TID, BP, CGC)                                              \
  {                                                                            \
    float m2v_ = m2s[(TID) * 64 + (CGC) * 16 + lr];                            \
    f32x4 ci_ = {m2v_, m2v_, m2v_, m2v_};                                      \
    BOp bu_;                                                                   \
    bu_.q[0] = *(const uint4*)((BP) + (CGC) * 2048 + l * 32);                  \
    bu_.q[1] = *(const uint4*)((BP) + (CGC) * 2048 + l * 32 + 16);             \
    _Pragma("unroll") for (int g_ = 0; g_ < 2; ++g_) {                         \
      f32x4 acc_ = __builtin_amdgcn_mfma_scale_f32_16x16x128_f8f6f4(           \
          af[g_], bu_.v, ci_, 0, 0, 0, 127, 0, 127);                           \
      _Pragma("unroll") for (int e_ = 0; e_ < 4; ++e_) {                       \
        bs[g_ * 4 + e_] = fmaxf(bs[g_ * 4 + e_], acc_[e_]);                    \
      }                                                                        \
    }                                                                          \
  }

  int cur = 0;
  for (int ks = 0; ks < NT; ++ks) {
    const int tid = (rot + ks) & 15;
    uint4 s0, s1;
    if (ks < NT - 1) {
      // issue next tile's global loads EARLY (latency hides under compute)
      const char* src = (const char*)mbf8 + (((rot + ks + 1) & 15) * TILEB);
      s0 = *(const uint4*)(src + t * 16);
      s1 = *(const uint4*)(src + 4096 + t * 16);
    }
    const char* bp = Bs[cur];
    COMPUTE_CGC(tid, bp, 0);
    COMPUTE_CGC(tid, bp, 1);
    if (ks < NT - 1) {
      // mid-tile write: staging regs die here; Bs[cur^1] not being read
      char* dst = Bs[cur ^ 1];
      *(uint4*)(dst + t * 16) = s0;
      *(uint4*)(dst + 4096 + t * 16) = s1;
    }
    COMPUTE_CGC(tid, bp, 2);
    COMPUTE_CGC(tid, bp, 3);
    __syncthreads();
    cur ^= 1;
  }
#undef COMPUTE_CGC

  // ---- per-row max across the 16 centroid-lanes, then loss contribution ----
  // slot (g, e) on lane (kq, lr) holds row g*16 + kq*4 + e (lanes lr share it)
  float lsum = 0.f;
#pragma unroll
  for (int e = 0; e < 8; ++e) {
    float m = bs[e];
#pragma unroll
    for (int s = 1; s < 16; s <<= 1) {
      float o = __shfl_xor(m, s, 64);
      m = fmaxf(m, o);
    }
    if (lr == 0) {
      int rowc = (e >> 2) * 16 + kq * 4 + (e & 3);
      lsum += x2s[w * 32 + rowc] - 2.0f * m;
    }
  }
  // wave sum (only lr==0 lanes carry nonzero lsum)
#pragma unroll
  for (int s = 32; s; s >>= 1) lsum += __shfl_down(lsum, s, 64);
  if (l == 0) wsum[w] = lsum;
  __syncthreads();
  if (t == 0) partials[blockIdx.x] = wsum[0] + wsum[1] + wsum[2] + wsum[3];
}

// Kernel 3: deterministic fixed-order final reduction (double accum).
__global__ void reduce_loss(const float* __restrict__ partials,
                            float* __restrict__ out) {
  __shared__ double ws[4];
  int t = threadIdx.x;
  double s = 0.0;
  for (int i = t; i < NBLK; i += 256) s += (double)partials[i];
#pragma unroll
  for (int m = 32; m; m >>= 1) s += __shfl_down(s, m, 64);
  if ((t & 63) == 0) ws[t >> 6] = s;
  __syncthreads();
  if (t == 0) out[0] = (float)(ws[0] + ws[1] + ws[2] + ws[3]);
}

extern "C" void kernel_launch(void* const* d_in, const int* in_sizes, int n_in,
                              void* d_out, int out_size, void* d_ws,
                              size_t ws_size, hipStream_t stream) {
  const float* X = (const float*)d_in[0];
  const float* means = (const float*)d_in[1];
  float* out = (float*)d_out;
  char* ws = (char*)d_ws;
  unsigned char* mbf8 = (unsigned char*)ws;         // 131072 B
  float* nm2 = (float*)(ws + 131072);               // 4096 B
  float* partials = (float*)(ws + 131072 + 4096);   // 8192 B

  prep_means<<<K_TOTAL, 64, 0, stream>>>(means, mbf8, nm2);
  kmeans_main<<<NBLK, 256, 0, stream>>>(X, mbf8, nm2, partials);
  reduce_loss<<<1, 256, 0, stream>>>(partials, out);
}